// Round 3
// baseline (183.798 us; speedup 1.0000x reference)
//
#include <hip/hip_runtime.h>

// Nearest-neighbor gather resample.
// idx:    [B, 2, N] float32 (row, col) coords
// source: [B, 640, 640, 3] float32
// out:    [B, N, 3] float32; zero where rounded coord out of bounds.
//
// Semantics: coord = (int)truncf(v + 0.5f)  -- trunc toward zero, matching
// jnp.trunc(idx+0.5).astype(int32). Validity tested on UNCLAMPED coord.
//
// R3 changes vs R2 (178us harness / 67us per dispatch):
//  - Plain (cacheable) out stores again: NT stores caused +21% WRITE_SIZE
//    (partial-line write-through; the 3 strided float4 stores per quad
//    need L2 to merge into full lines).
//  - 8 px/thread: halves wave count, doubles per-wave gather MLP
//    (8 independent line-requests in flight per lane), halves idx-load
//    instruction count.
//  - Explicit <3 x float> (dwordx3) gather per pixel: exactly one VMEM
//    instruction and one line-request per pixel, 12B exact (never OOB).
//  - Keep: XCD batch-affinity swizzle (FETCH 191->83 MB), NT idx loads.

#define HS 640
#define WS 640
#define NC 3
#define NXCD 8
#define PXT 8   // pixels per thread

typedef float v4f __attribute__((ext_vector_type(4)));
typedef float v3f __attribute__((ext_vector_type(3), aligned(4)));

__global__ __launch_bounds__(256) void resample_nn_kernel(
    const float* __restrict__ idx,   // [B, 2, N]
    const float* __restrict__ src,   // [B, HS, WS, NC]
    float* __restrict__ out,         // [B, N, NC]
    int N)                           // pixels per batch (divisible by 8)
{
    const int thr_per_b = N >> 3;    // threads per batch

    // --- XCD batch-affinity swizzle (bijective when gridDim.x % 8 == 0) ---
    int bid = blockIdx.x;
    int nb  = gridDim.x;
    if ((nb & (NXCD - 1)) == 0) {
        int per = nb >> 3;                       // blocks per XCD
        bid = (bid & (NXCD - 1)) * per + (bid >> 3);
    }

    long long tid = (long long)bid * blockDim.x + threadIdx.x;
    int b = (int)(tid / thr_per_b);
    int o = (int)(tid % thr_per_b);
    int n0 = o << 3;

    const float* idx_b = idx + (size_t)b * 2 * N;
    // idx is read exactly once -> nontemporal so it doesn't pollute the
    // caches that the source gather depends on.
    v4f r0 = __builtin_nontemporal_load((const v4f*)(idx_b + n0));
    v4f r1 = __builtin_nontemporal_load((const v4f*)(idx_b + n0 + 4));
    v4f c0 = __builtin_nontemporal_load((const v4f*)(idx_b + N + n0));
    v4f c1 = __builtin_nontemporal_load((const v4f*)(idx_b + N + n0 + 4));

    const float* src_b = src + (size_t)b * (HS * WS * NC);

    float rr[PXT] = {r0.x, r0.y, r0.z, r0.w, r1.x, r1.y, r1.z, r1.w};
    float cc[PXT] = {c0.x, c0.y, c0.z, c0.w, c1.x, c1.y, c1.z, c1.w};

    // Compute all addresses + validity first, then issue all 8 gathers
    // back-to-back so they are all in flight together.
    const v3f* p[PXT];
    bool valid[PXT];
#pragma unroll
    for (int i = 0; i < PXT; ++i) {
        // trunc-toward-zero conversion == jnp.trunc().astype(int32)
        int ir = (int)(rr[i] + 0.5f);
        int ic = (int)(cc[i] + 0.5f);
        valid[i] = (ir >= 0) & (ic >= 0) & (ir < HS) & (ic < WS);
        int irc = min(max(ir, 0), HS - 1);
        int icc = min(max(ic, 0), WS - 1);
        p[i] = (const v3f*)(src_b + ((size_t)irc * WS + icc) * NC);
    }

    v3f g[PXT];
#pragma unroll
    for (int i = 0; i < PXT; ++i) g[i] = *p[i];     // 8 independent dwordx3

    float v[3 * PXT];
#pragma unroll
    for (int i = 0; i < PXT; ++i) {
        v[3 * i + 0] = valid[i] ? g[i].x : 0.0f;
        v[3 * i + 1] = valid[i] ? g[i].y : 0.0f;
        v[3 * i + 2] = valid[i] ? g[i].z : 0.0f;
    }

    // 24 contiguous floats per thread -> 6 float4 stores, cacheable so L2
    // merges the strided lane pattern into full lines.
    v4f* ov = (v4f*)(out + ((size_t)b * N + n0) * NC);
#pragma unroll
    for (int j = 0; j < 6; ++j) {
        v4f t = {v[4 * j + 0], v[4 * j + 1], v[4 * j + 2], v[4 * j + 3]};
        ov[j] = t;
    }
}

extern "C" void kernel_launch(void* const* d_in, const int* in_sizes, int n_in,
                              void* d_out, int out_size, void* d_ws, size_t ws_size,
                              hipStream_t stream) {
    const float* idx = (const float*)d_in[0];
    const float* src = (const float*)d_in[1];
    float* out = (float*)d_out;

    // source is [B, 640, 640, 3]; idx is [B, 2, N]
    int B = in_sizes[1] / (HS * WS * NC);        // 16
    int N = in_sizes[0] / (2 * B);               // 262144

    long long total_thr = (long long)B * (N >> 3);     // 524,288 threads
    int block = 256;
    int grid = (int)((total_thr + block - 1) / block); // 2048 (div by 8)

    resample_nn_kernel<<<grid, block, 0, stream>>>(idx, src, out, N);
}

// Round 5
// 181.519 us; speedup vs baseline: 1.0126x; 1.0126x over previous
//
#include <hip/hip_runtime.h>

// Nearest-neighbor gather resample.
// idx:    [B, 2, N] float32 (row, col) coords
// source: [B, 640, 640, 3] float32
// out:    [B, N, 3] float32; zero where rounded coord out of bounds.
//
// Semantics: coord = (int)truncf(v + 0.5f)  -- trunc toward zero, matching
// jnp.trunc(idx+0.5).astype(int32). Validity tested on UNCLAMPED coord.
//
// R5 == R4 (infra failure last round; never ran).
// R4: latency-bound random-gather theory. dur was pinned 67-71us across
// R0-R3 while hbm_bytes swung 241->144 MB: traffic is NOT the limiter;
// per-CU outstanding-miss concurrency is. Changes:
//  - 4 px/thread (R2's best: 16K waves; R3's 8px was slower).
//  - block=64 (1 wave/block, 16384 blocks): wave-granularity backfill ->
//    smoother ramp/drain, higher time-avg occupancy (was 51-67%).
//  - Keep: dwordx3 gather (1 line-request/px), cacheable out stores
//    (NT stores cost +21% WRITE_SIZE in R2), NT idx loads, XCD
//    batch-affinity swizzle (FETCH 191->83 MB vs baseline).

#define HS 640
#define WS 640
#define NC 3
#define NXCD 8

typedef float v4f __attribute__((ext_vector_type(4)));
typedef float v3f __attribute__((ext_vector_type(3), aligned(4)));

__global__ __launch_bounds__(64) void resample_nn_kernel(
    const float* __restrict__ idx,   // [B, 2, N]
    const float* __restrict__ src,   // [B, HS, WS, NC]
    float* __restrict__ out,         // [B, N, NC]
    int N)                           // pixels per batch (quad-divisible)
{
    const int quads_per_b = N >> 2;

    // --- XCD batch-affinity swizzle (bijective when gridDim.x % 8 == 0) ---
    int bid = blockIdx.x;
    int nb  = gridDim.x;
    if ((nb & (NXCD - 1)) == 0) {
        int per = nb >> 3;                       // blocks per XCD
        bid = (bid & (NXCD - 1)) * per + (bid >> 3);
    }

    long long tid = (long long)bid * blockDim.x + threadIdx.x;
    int b = (int)(tid / quads_per_b);
    int q = (int)(tid % quads_per_b);
    int n0 = q << 2;

    const float* idx_b = idx + (size_t)b * 2 * N;
    // idx is read exactly once -> nontemporal so it doesn't pollute the
    // caches that the source gather depends on.
    v4f r4 = __builtin_nontemporal_load((const v4f*)(idx_b + n0));
    v4f c4 = __builtin_nontemporal_load((const v4f*)(idx_b + N + n0));

    const float* src_b = src + (size_t)b * (HS * WS * NC);

    float rr[4] = {r4.x, r4.y, r4.z, r4.w};
    float cc[4] = {c4.x, c4.y, c4.z, c4.w};

    // Compute all addresses + validity first, then issue all 4 gathers
    // back-to-back so they are all in flight together.
    const v3f* p[4];
    bool valid[4];
#pragma unroll
    for (int i = 0; i < 4; ++i) {
        // trunc-toward-zero conversion == jnp.trunc().astype(int32)
        int ir = (int)(rr[i] + 0.5f);
        int ic = (int)(cc[i] + 0.5f);
        valid[i] = (ir >= 0) & (ic >= 0) & (ir < HS) & (ic < WS);
        int irc = min(max(ir, 0), HS - 1);
        int icc = min(max(ic, 0), WS - 1);
        p[i] = (const v3f*)(src_b + ((size_t)irc * WS + icc) * NC);
    }

    v3f g[4];
#pragma unroll
    for (int i = 0; i < 4; ++i) g[i] = *p[i];     // 4 independent dwordx3

    float v[12];
#pragma unroll
    for (int i = 0; i < 4; ++i) {
        v[3 * i + 0] = valid[i] ? g[i].x : 0.0f;
        v[3 * i + 1] = valid[i] ? g[i].y : 0.0f;
        v[3 * i + 2] = valid[i] ? g[i].z : 0.0f;
    }

    // 12 contiguous floats per thread -> 3 float4 stores, cacheable so L2
    // merges the strided lane pattern into full lines.
    v4f* ov = (v4f*)(out + ((size_t)b * N + n0) * NC);
    v4f o0 = {v[0], v[1], v[2], v[3]};
    v4f o1 = {v[4], v[5], v[6], v[7]};
    v4f o2 = {v[8], v[9], v[10], v[11]};
    ov[0] = o0;
    ov[1] = o1;
    ov[2] = o2;
}

extern "C" void kernel_launch(void* const* d_in, const int* in_sizes, int n_in,
                              void* d_out, int out_size, void* d_ws, size_t ws_size,
                              hipStream_t stream) {
    const float* idx = (const float*)d_in[0];
    const float* src = (const float*)d_in[1];
    float* out = (float*)d_out;

    // source is [B, 640, 640, 3]; idx is [B, 2, N]
    int B = in_sizes[1] / (HS * WS * NC);        // 16
    int N = in_sizes[0] / (2 * B);               // 262144

    long long total_thr = (long long)B * (N >> 2);     // 1,048,576 threads
    int block = 64;                                    // 1 wave per block
    int grid = (int)((total_thr + block - 1) / block); // 16384 (div by 8)

    resample_nn_kernel<<<grid, block, 0, stream>>>(idx, src, out, N);
}

// Round 6
// 179.845 us; speedup vs baseline: 1.0220x; 1.0093x over previous
//
#include <hip/hip_runtime.h>

// Nearest-neighbor gather resample.
// idx:    [B, 2, N] float32 (row, col) coords
// source: [B, 640, 640, 3] float32
// out:    [B, N, 3] float32; zero where rounded coord out of bounds.
//
// Semantics: coord = (int)truncf(v + 0.5f)  -- trunc toward zero, matching
// jnp.trunc(idx+0.5).astype(int32). Validity tested on UNCLAMPED coord.
//
// R6: single-variable change vs R5 (67.2us/dispatch): gather loads issued
// as inline-asm `global_load_dwordx3 ... sc0` -> L1-BYPASS.
// Evidence for this lever: dur pinned 67-71us across R0-R5 while traffic,
// block size, px/thread, and request count all varied; R2 (3 scalar req/px)
// == R5 (1 dwordx3 req/px) proves the limiter tracks LINES not requests ->
// per-CU L1 MSHR line cap (~32 in flight at ~300cy latency = observed
// ~10cy/line/CU). sc0 skips L1 allocation; random 12B picks had ~1% L1
// hit rate so no downside. Explicit vmcnt(0) before use (compiler does
// not track inline-asm loads).
// Keep from R2-R5: XCD batch-affinity swizzle, NT idx loads, cacheable
// full-line out stores, 4 px/thread, block=64.

#define HS 640
#define WS 640
#define NC 3
#define NXCD 8

typedef float v4f __attribute__((ext_vector_type(4)));
typedef float v3f __attribute__((ext_vector_type(3)));

__global__ __launch_bounds__(64) void resample_nn_kernel(
    const float* __restrict__ idx,   // [B, 2, N]
    const float* __restrict__ src,   // [B, HS, WS, NC]
    float* __restrict__ out,         // [B, N, NC]
    int N)                           // pixels per batch (quad-divisible)
{
    const int quads_per_b = N >> 2;

    // --- XCD batch-affinity swizzle (bijective when gridDim.x % 8 == 0) ---
    int bid = blockIdx.x;
    int nb  = gridDim.x;
    if ((nb & (NXCD - 1)) == 0) {
        int per = nb >> 3;                       // blocks per XCD
        bid = (bid & (NXCD - 1)) * per + (bid >> 3);
    }

    long long tid = (long long)bid * blockDim.x + threadIdx.x;
    int b = (int)(tid / quads_per_b);
    int q = (int)(tid % quads_per_b);
    int n0 = q << 2;

    const float* idx_b = idx + (size_t)b * 2 * N;
    // idx is read exactly once -> nontemporal so it doesn't pollute the
    // caches that the source gather depends on.
    v4f r4 = __builtin_nontemporal_load((const v4f*)(idx_b + n0));
    v4f c4 = __builtin_nontemporal_load((const v4f*)(idx_b + N + n0));

    const float* src_b = src + (size_t)b * (HS * WS * NC);

    float rr[4] = {r4.x, r4.y, r4.z, r4.w};
    float cc[4] = {c4.x, c4.y, c4.z, c4.w};

    // Compute all addresses + validity first, then issue all 4 gathers
    // back-to-back so they are all in flight together.
    const float* p[4];
    bool valid[4];
#pragma unroll
    for (int i = 0; i < 4; ++i) {
        // trunc-toward-zero conversion == jnp.trunc().astype(int32)
        int ir = (int)(rr[i] + 0.5f);
        int ic = (int)(cc[i] + 0.5f);
        valid[i] = (ir >= 0) & (ic >= 0) & (ir < HS) & (ic < WS);
        int irc = min(max(ir, 0), HS - 1);
        int icc = min(max(ic, 0), WS - 1);
        p[i] = src_b + ((size_t)irc * WS + icc) * NC;
    }

    // L1-bypass (sc0) gathers: skip L1 MSHR allocation, service from L2.
    // All 4 issued back-to-back, then one drain.
    v3f g0, g1, g2, g3;
    asm volatile("global_load_dwordx3 %0, %1, off sc0" : "=&v"(g0) : "v"(p[0]));
    asm volatile("global_load_dwordx3 %0, %1, off sc0" : "=&v"(g1) : "v"(p[1]));
    asm volatile("global_load_dwordx3 %0, %1, off sc0" : "=&v"(g2) : "v"(p[2]));
    asm volatile("global_load_dwordx3 %0, %1, off sc0" : "=&v"(g3) : "v"(p[3]));
    asm volatile("s_waitcnt vmcnt(0)" ::: "memory");
    __builtin_amdgcn_sched_barrier(0);   // keep consumers below the waitcnt

    v3f g[4] = {g0, g1, g2, g3};
    float v[12];
#pragma unroll
    for (int i = 0; i < 4; ++i) {
        v[3 * i + 0] = valid[i] ? g[i].x : 0.0f;
        v[3 * i + 1] = valid[i] ? g[i].y : 0.0f;
        v[3 * i + 2] = valid[i] ? g[i].z : 0.0f;
    }

    // 12 contiguous floats per thread -> 3 float4 stores, cacheable so L2
    // merges the strided lane pattern into full lines.
    v4f* ov = (v4f*)(out + ((size_t)b * N + n0) * NC);
    v4f o0 = {v[0], v[1], v[2], v[3]};
    v4f o1 = {v[4], v[5], v[6], v[7]};
    v4f o2 = {v[8], v[9], v[10], v[11]};
    ov[0] = o0;
    ov[1] = o1;
    ov[2] = o2;
}

extern "C" void kernel_launch(void* const* d_in, const int* in_sizes, int n_in,
                              void* d_out, int out_size, void* d_ws, size_t ws_size,
                              hipStream_t stream) {
    const float* idx = (const float*)d_in[0];
    const float* src = (const float*)d_in[1];
    float* out = (float*)d_out;

    // source is [B, 640, 640, 3]; idx is [B, 2, N]
    int B = in_sizes[1] / (HS * WS * NC);        // 16
    int N = in_sizes[0] / (2 * B);               // 262144

    long long total_thr = (long long)B * (N >> 2);     // 1,048,576 threads
    int block = 64;                                    // 1 wave per block
    int grid = (int)((total_thr + block - 1) / block); // 16384 (div by 8)

    resample_nn_kernel<<<grid, block, 0, stream>>>(idx, src, out, N);
}